// Round 1
// baseline (636.921 us; speedup 1.0000x reference)
//
#include <hip/hip_runtime.h>
#include <cstdint>

// Problem dims (fixed by reference)
#define BB 4
#define SS 2048
#define HH 1024
#define FF 4096
#define MM (BB * SS)   // 8192 tokens

typedef __attribute__((ext_vector_type(8))) short bf16x8;
typedef __attribute__((ext_vector_type(4))) float f32x4;

__device__ __forceinline__ unsigned short f2b(float f) {
  union { float f; unsigned u; } v; v.f = f;
  unsigned r = v.u + 0x7FFFu + ((v.u >> 16) & 1u);   // round-nearest-even
  return (unsigned short)(r >> 16);
}

__device__ __forceinline__ void gld16(const void* g, void* l) {
  __builtin_amdgcn_global_load_lds(
      (const __attribute__((address_space(1))) void*)g,
      (__attribute__((address_space(3))) void*)l, 16, 0, 0);
}

// ---------- elementwise fp32 -> bf16 ----------
__global__ __launch_bounds__(256) void conv_f2b_kernel(
    const float* __restrict__ in, unsigned short* __restrict__ out, long n4) {
  long i = (long)blockIdx.x * 256 + threadIdx.x;
  if (i >= n4) return;
  const float4 f = ((const float4*)in)[i];
  ushort4 o;
  o.x = f2b(f.x); o.y = f2b(f.y); o.z = f2b(f.z); o.w = f2b(f.w);
  ((ushort4*)out)[i] = o;
}

// ---------- transpose fp32 [R,C] -> bf16 [C,R] ----------
__global__ __launch_bounds__(256) void transpose_f2b_kernel(
    const float* __restrict__ in, unsigned short* __restrict__ out, int R, int C) {
  __shared__ float t[32][33];
  int bc = blockIdx.x * 32;
  int br = blockIdx.y * 32;
  int x = threadIdx.x;   // 0..31
  int y0 = threadIdx.y;  // 0..7
#pragma unroll
  for (int yy = y0; yy < 32; yy += 8)
    t[yy][x] = in[(long)(br + yy) * C + bc + x];
  __syncthreads();
#pragma unroll
  for (int yy = y0; yy < 32; yy += 8)
    out[(long)(bc + yy) * R + br + x] = f2b(t[x][yy]);
}

// ---------- bf16 MFMA GEMM: C[M,N] = A[M,K] * B[N,K]^T (m97 structure) ----------
// 128x128 tile, 4 waves in 2x2, each wave 64x64 via 4x4 of 16x16x32 MFMA.
template <int OUT_BF16, int RELU, int HAS_BIAS, int HAS_RES>
__global__ __launch_bounds__(256) void gemm_bt_kernel(
    const unsigned short* __restrict__ A, long lda, long sA,
    const unsigned short* __restrict__ Bm, long ldb, long sB,
    void* __restrict__ Cm, long ldc, long sC,
    const float* __restrict__ bias,
    const float* __restrict__ res, long ldr,
    float scale, int K) {
  __shared__ unsigned short As[128 * 32];
  __shared__ unsigned short Bs[128 * 32];
  const int tid = threadIdx.x;
  const int lane = tid & 63;
  const int wave = tid >> 6;
  const long bm = (long)blockIdx.y * 128;
  const long bn = (long)blockIdx.x * 128;
  const int z = blockIdx.z;

  // staging: thread t loads 16B chunk t (rows tid/4, cols (tid&3)*8) and chunk t+256 (+64 rows)
  const unsigned short* Ap = A + (long)z * sA + (bm + (tid >> 2)) * lda + ((tid & 3) * 8);
  const unsigned short* Bp = Bm + (long)z * sB + (bn + (tid >> 2)) * ldb + ((tid & 3) * 8);
  unsigned short* asd = As + tid * 8;
  unsigned short* bsd = Bs + tid * 8;
  const long a64 = 64 * lda;
  const long b64 = 64 * ldb;

  f32x4 acc[4][4];
#pragma unroll
  for (int i = 0; i < 4; ++i)
#pragma unroll
    for (int j = 0; j < 4; ++j) acc[i][j] = (f32x4){0.f, 0.f, 0.f, 0.f};

  const int mo = (wave >> 1) * 64;
  const int no = (wave & 1) * 64;
  const int fr = lane & 15;
  const int fq = (lane >> 4) * 8;

  for (int k0 = 0; k0 < K; k0 += 32) {
    __syncthreads();
    gld16(Ap + k0, asd);
    gld16(Ap + a64 + k0, asd + 2048);
    gld16(Bp + k0, bsd);
    gld16(Bp + b64 + k0, bsd + 2048);
    __syncthreads();
    bf16x8 af[4], bfr[4];
#pragma unroll
    for (int i = 0; i < 4; ++i)
      af[i] = *(const bf16x8*)&As[(mo + i * 16 + fr) * 32 + fq];
#pragma unroll
    for (int i = 0; i < 4; ++i)
      bfr[i] = *(const bf16x8*)&Bs[(no + i * 16 + fr) * 32 + fq];
#pragma unroll
    for (int mi = 0; mi < 4; ++mi)
#pragma unroll
      for (int ni = 0; ni < 4; ++ni)
        acc[mi][ni] = __builtin_amdgcn_mfma_f32_16x16x32_bf16(af[mi], bfr[ni], acc[mi][ni], 0, 0, 0);
  }

  // epilogue: C/D layout col=lane&15, row=(lane>>4)*4+reg (m89-verified)
  const long crow = bm + mo + ((lane >> 4) * 4);
  const long ccol = bn + no + (lane & 15);
#pragma unroll
  for (int mi = 0; mi < 4; ++mi) {
#pragma unroll
    for (int ni = 0; ni < 4; ++ni) {
      const long col = ccol + ni * 16;
      const float bv = HAS_BIAS ? bias[col] : 0.f;
#pragma unroll
      for (int r = 0; r < 4; ++r) {
        const long row = crow + mi * 16 + r;
        float v = acc[mi][ni][r] * scale + bv;
        if (HAS_RES) v += res[row * ldr + col];
        if (RELU) v = fmaxf(v, 0.f);
        if (OUT_BF16)
          ((unsigned short*)Cm)[(long)z * sC + row * ldc + col] = f2b(v);
        else
          ((float*)Cm)[(long)z * sC + row * ldc + col] = v;
      }
    }
  }
}

// ---------- row softmax over S with mask add, fp32 in -> bf16 out ----------
__global__ __launch_bounds__(256) void softmax_kernel(
    const float* __restrict__ Sf, const float* __restrict__ mask,
    unsigned short* __restrict__ Ab) {
  const long row = blockIdx.x;          // 0..MM-1 (b*SS+q)
  const int q = (int)(row & (SS - 1));
  const float* sr = Sf + row * SS;
  const float* mr = mask + (long)q * SS;
  const int tid = threadIdx.x;
  float v[8];
  float mx = -1e30f;
#pragma unroll
  for (int i = 0; i < 8; ++i) {
    int c = tid + i * 256;
    v[i] = sr[c] + mr[c];
    mx = fmaxf(mx, v[i]);
  }
#pragma unroll
  for (int off = 32; off > 0; off >>= 1) mx = fmaxf(mx, __shfl_xor(mx, off, 64));
  __shared__ float rm[4], rs[4];
  if ((tid & 63) == 0) rm[tid >> 6] = mx;
  __syncthreads();
  mx = fmaxf(fmaxf(rm[0], rm[1]), fmaxf(rm[2], rm[3]));
  float sum = 0.f;
#pragma unroll
  for (int i = 0; i < 8; ++i) { v[i] = __expf(v[i] - mx); sum += v[i]; }
#pragma unroll
  for (int off = 32; off > 0; off >>= 1) sum += __shfl_xor(sum, off, 64);
  if ((tid & 63) == 0) rs[tid >> 6] = sum;
  __syncthreads();
  sum = rs[0] + rs[1] + rs[2] + rs[3];
  const float inv = 1.f / sum;
  unsigned short* ar = Ab + row * SS;
#pragma unroll
  for (int i = 0; i < 8; ++i) ar[tid + i * 256] = f2b(v[i] * inv);
}

// ---------- in-place LayerNorm over H=1024 ----------
__global__ __launch_bounds__(256) void layernorm_kernel(
    float* __restrict__ Y, const float* __restrict__ g, const float* __restrict__ b) {
  const long row = blockIdx.x;
  float* y = Y + row * HH;
  const int tid = threadIdx.x;
  float v[4];
  float s = 0.f, ss = 0.f;
#pragma unroll
  for (int i = 0; i < 4; ++i) {
    v[i] = y[tid + i * 256];
    s += v[i]; ss += v[i] * v[i];
  }
#pragma unroll
  for (int off = 32; off > 0; off >>= 1) {
    s += __shfl_xor(s, off, 64);
    ss += __shfl_xor(ss, off, 64);
  }
  __shared__ float r1[4], r2[4];
  if ((tid & 63) == 0) { r1[tid >> 6] = s; r2[tid >> 6] = ss; }
  __syncthreads();
  s = r1[0] + r1[1] + r1[2] + r1[3];
  ss = r2[0] + r2[1] + r2[2] + r2[3];
  const float mu = s * (1.f / HH);
  const float var = ss * (1.f / HH) - mu * mu;
  const float rinv = rsqrtf(var + 1e-5f);
#pragma unroll
  for (int i = 0; i < 4; ++i) {
    int c = tid + i * 256;
    y[c] = (v[i] - mu) * rinv * g[c] + b[c];
  }
}

extern "C" void kernel_launch(void* const* d_in, const int* in_sizes, int n_in,
                              void* d_out, int out_size, void* d_ws, size_t ws_size,
                              hipStream_t stream) {
  (void)in_sizes; (void)n_in; (void)out_size; (void)ws_size;
  const float* x     = (const float*)d_in[0];
  const float* mask  = (const float*)d_in[1];
  const float* qW    = (const float*)d_in[2];
  const float* qb    = (const float*)d_in[3];
  const float* kW    = (const float*)d_in[4];
  const float* kb    = (const float*)d_in[5];
  const float* vW    = (const float*)d_in[6];
  const float* vb    = (const float*)d_in[7];
  const float* w1    = (const float*)d_in[8];
  const float* b1    = (const float*)d_in[9];
  const float* w2    = (const float*)d_in[10];
  const float* b2    = (const float*)d_in[11];
  const float* gamma = (const float*)d_in[12];
  const float* beta  = (const float*)d_in[13];
  float* out = (float*)d_out;

  char* ws = (char*)d_ws;
  size_t o = 0;
  auto alloc = [&](size_t bytes) { void* p = ws + o; o += (bytes + 255) & ~(size_t)255; return p; };
  unsigned short* qWt = (unsigned short*)alloc((size_t)HH * HH * 2);   // [H][H]  (N,K)
  unsigned short* kWt = (unsigned short*)alloc((size_t)HH * HH * 2);
  unsigned short* vWt = (unsigned short*)alloc((size_t)HH * HH * 2);
  unsigned short* w1t = (unsigned short*)alloc((size_t)FF * HH * 2);   // [F][H]
  unsigned short* w2t = (unsigned short*)alloc((size_t)HH * FF * 2);   // [H][F]
  unsigned short* xb  = (unsigned short*)alloc((size_t)MM * HH * 2);   // later reused as attn bf16
  unsigned short* Qb  = (unsigned short*)alloc((size_t)MM * HH * 2);
  unsigned short* Kb  = (unsigned short*)alloc((size_t)MM * HH * 2);
  float*          Vf  = (float*)alloc((size_t)MM * HH * 4);            // later reused as attn fp32
  unsigned short* Vt  = (unsigned short*)alloc((size_t)HH * MM * 2);   // [H][M] V^T
  float*          Sf  = (float*)alloc((size_t)BB * SS * SS * 4);       // later reused as h bf16
  unsigned short* Ab  = (unsigned short*)alloc((size_t)BB * SS * SS * 2);
  float*          attnf = Vf;              // [M,H] fp32 (after A*V)
  unsigned short* attnb = xb;              // [M,H] bf16
  unsigned short* hb    = (unsigned short*)Sf;  // [M,F] bf16 (64MB fits exactly)

  const dim3 tb(32, 8);

  // 1. x -> bf16
  conv_f2b_kernel<<<MM * HH / 1024, 256, 0, stream>>>(x, xb, (long)MM * HH / 4);
  // 2. weight transposes (fp32 [K,N] -> bf16 [N,K])
  transpose_f2b_kernel<<<dim3(HH / 32, HH / 32), tb, 0, stream>>>(qW, qWt, HH, HH);
  transpose_f2b_kernel<<<dim3(HH / 32, HH / 32), tb, 0, stream>>>(kW, kWt, HH, HH);
  transpose_f2b_kernel<<<dim3(HH / 32, HH / 32), tb, 0, stream>>>(vW, vWt, HH, HH);
  transpose_f2b_kernel<<<dim3(FF / 32, HH / 32), tb, 0, stream>>>(w1, w1t, HH, FF);
  transpose_f2b_kernel<<<dim3(HH / 32, FF / 32), tb, 0, stream>>>(w2, w2t, FF, HH);
  // 3. Q, K (bf16 out), V (fp32 out)
  gemm_bt_kernel<1, 0, 1, 0><<<dim3(HH / 128, MM / 128, 1), 256, 0, stream>>>(
      xb, HH, 0, qWt, HH, 0, Qb, HH, 0, qb, nullptr, 0, 1.f, HH);
  gemm_bt_kernel<1, 0, 1, 0><<<dim3(HH / 128, MM / 128, 1), 256, 0, stream>>>(
      xb, HH, 0, kWt, HH, 0, Kb, HH, 0, kb, nullptr, 0, 1.f, HH);
  gemm_bt_kernel<0, 0, 1, 0><<<dim3(HH / 128, MM / 128, 1), 256, 0, stream>>>(
      xb, HH, 0, vWt, HH, 0, Vf, HH, 0, vb, nullptr, 0, 1.f, HH);
  // 4. V^T  (fp32 [M,H] -> bf16 [H,M])
  transpose_f2b_kernel<<<dim3(HH / 32, MM / 32), tb, 0, stream>>>(Vf, Vt, MM, HH);
  // 5. S = Q K^T / sqrt(H), batched over BB
  gemm_bt_kernel<0, 0, 0, 0><<<dim3(SS / 128, SS / 128, BB), 256, 0, stream>>>(
      Qb, HH, (long)SS * HH, Kb, HH, (long)SS * HH, Sf, SS, (long)SS * SS,
      nullptr, nullptr, 0, 0.03125f, HH);
  // 6. A = softmax(S + mask) -> bf16
  softmax_kernel<<<MM, 256, 0, stream>>>(Sf, mask, Ab);
  // 7. attn = A V, batched (B = Vt column slice per batch: strideB=SS elems, ldb=MM)
  gemm_bt_kernel<0, 0, 0, 0><<<dim3(HH / 128, SS / 128, BB), 256, 0, stream>>>(
      Ab, SS, (long)SS * SS, Vt, MM, SS, attnf, HH, (long)SS * HH,
      nullptr, nullptr, 0, 1.f, SS);
  // 8. attn -> bf16
  conv_f2b_kernel<<<MM * HH / 1024, 256, 0, stream>>>(attnf, attnb, (long)MM * HH / 4);
  // 9. h = relu(attn w1 + b1) -> bf16
  gemm_bt_kernel<1, 1, 1, 0><<<dim3(FF / 128, MM / 128, 1), 256, 0, stream>>>(
      attnb, HH, 0, w1t, HH, 0, hb, FF, 0, b1, nullptr, 0, 1.f, HH);
  // 10. y = attn + h w2 + b2 -> fp32 out
  gemm_bt_kernel<0, 0, 1, 1><<<dim3(HH / 128, MM / 128, 1), 256, 0, stream>>>(
      hb, FF, 0, w2t, FF, 0, out, HH, 0, b2, attnf, HH, 1.f, FF);
  // 11. LayerNorm in place
  layernorm_kernel<<<MM, 256, 0, stream>>>(out, gamma, beta);
}

// Round 2
// 594.554 us; speedup vs baseline: 1.0713x; 1.0713x over previous
//
#include <hip/hip_runtime.h>
#include <cstdint>

// Problem dims (fixed by reference)
#define BB 4
#define SS 2048
#define HH 1024
#define FF 4096
#define MM (BB * SS)   // 8192 tokens

typedef __attribute__((ext_vector_type(8))) short bf16x8;
typedef __attribute__((ext_vector_type(4))) float f32x4;

__device__ __forceinline__ unsigned short f2b(float f) {
  union { float f; unsigned u; } v; v.f = f;
  unsigned r = v.u + 0x7FFFu + ((v.u >> 16) & 1u);   // round-nearest-even
  return (unsigned short)(r >> 16);
}

__device__ __forceinline__ void gld16(const void* g, void* l) {
  __builtin_amdgcn_global_load_lds(
      (const __attribute__((address_space(1))) void*)g,
      (__attribute__((address_space(3))) void*)l, 16, 0, 0);
}

// ---------- elementwise fp32 -> bf16 ----------
__global__ __launch_bounds__(256) void conv_f2b_kernel(
    const float* __restrict__ in, unsigned short* __restrict__ out, long n4) {
  long i = (long)blockIdx.x * 256 + threadIdx.x;
  if (i >= n4) return;
  const float4 f = ((const float4*)in)[i];
  ushort4 o;
  o.x = f2b(f.x); o.y = f2b(f.y); o.z = f2b(f.z); o.w = f2b(f.w);
  ((ushort4*)out)[i] = o;
}

// ---------- transpose fp32 [R,C] -> bf16 [C,R] (ld_in = C, ld_out = R) ----------
__global__ __launch_bounds__(256) void transpose_f2b_kernel(
    const float* __restrict__ in, unsigned short* __restrict__ out, int R, int C) {
  __shared__ float t[32][33];
  int bc = blockIdx.x * 32;
  int br = blockIdx.y * 32;
  int x = threadIdx.x;   // 0..31
  int y0 = threadIdx.y;  // 0..7
#pragma unroll
  for (int yy = y0; yy < 32; yy += 8)
    t[yy][x] = in[(long)(br + yy) * C + bc + x];
  __syncthreads();
#pragma unroll
  for (int yy = y0; yy < 32; yy += 8)
    out[(long)(bc + yy) * R + br + x] = f2b(t[x][yy]);
}

// ---------- transpose bf16 [R,C] slice (ld_in given) -> bf16 [C,R] ----------
__global__ __launch_bounds__(256) void transpose_b2b_kernel(
    const unsigned short* __restrict__ in, long ldin,
    unsigned short* __restrict__ out, int R, int C) {
  __shared__ unsigned short t[32][33];
  int bc = blockIdx.x * 32;
  int br = blockIdx.y * 32;
  int x = threadIdx.x;
  int y0 = threadIdx.y;
#pragma unroll
  for (int yy = y0; yy < 32; yy += 8)
    t[yy][x] = in[(long)(br + yy) * ldin + bc + x];
  __syncthreads();
#pragma unroll
  for (int yy = y0; yy < 32; yy += 8)
    out[(long)(bc + yy) * R + br + x] = t[x][yy];
}

// ---------- concat 3 bias vectors [HH] -> [3*HH] ----------
__global__ __launch_bounds__(256) void concat3_kernel(
    const float* __restrict__ a, const float* __restrict__ b,
    const float* __restrict__ c, float* __restrict__ o) {
  int i = blockIdx.x * 256 + threadIdx.x;   // 0..3071
  float v = (i < HH) ? a[i] : (i < 2 * HH) ? b[i - HH] : c[i - 2 * HH];
  o[i] = v;
}

// ---------- bf16 MFMA GEMM: C[M,N] = A[M,K] * B[N,K]^T ----------
// 128x128 tile, 4 waves 2x2, each wave 64x64 via 4x4 of 16x16x32 MFMA.
// BK=64 as two stacked BK=32 sub-tiles (preserves gld16 lane-contiguity and
// m97 bank behavior; halves barrier count vs BK=32).
// OUT_MODE: 0 = fp32 out, 1 = bf16 out, 2 = fp32 out + bf16 secondary (C2)
template <int OUT_MODE, int RELU, int HAS_BIAS, int HAS_RES>
__global__ __launch_bounds__(256) void gemm_bt_kernel(
    const unsigned short* __restrict__ A, long lda, long sA,
    const unsigned short* __restrict__ Bm, long ldb, long sB,
    void* __restrict__ Cm, long ldc, long sC,
    unsigned short* __restrict__ C2,
    const float* __restrict__ bias,
    const float* __restrict__ res, long ldr,
    float scale, int K) {
  __shared__ unsigned short As[2 * 128 * 32];   // [sub-tile 0 | sub-tile 1]
  __shared__ unsigned short Bs[2 * 128 * 32];
  const int tid = threadIdx.x;
  const int lane = tid & 63;
  const int wave = tid >> 6;
  const long bm = (long)blockIdx.y * 128;
  const long bn = (long)blockIdx.x * 128;
  const int z = blockIdx.z;

  // staging thread map (per BK=32 sub-tile): row = tid>>2, col chunk = (tid&3)*8
  const unsigned short* Ap = A + (long)z * sA + (bm + (tid >> 2)) * lda + ((tid & 3) * 8);
  const unsigned short* Bp = Bm + (long)z * sB + (bn + (tid >> 2)) * ldb + ((tid & 3) * 8);
  unsigned short* asd = As + tid * 8;
  unsigned short* bsd = Bs + tid * 8;
  const long a64 = 64 * lda;
  const long b64 = 64 * ldb;

  f32x4 acc[4][4];
#pragma unroll
  for (int i = 0; i < 4; ++i)
#pragma unroll
    for (int j = 0; j < 4; ++j) acc[i][j] = (f32x4){0.f, 0.f, 0.f, 0.f};

  const int mo = (wave >> 1) * 64;
  const int no = (wave & 1) * 64;
  const int fr = lane & 15;
  const int fq = (lane >> 4) * 8;

  for (int k0 = 0; k0 < K; k0 += 64) {
    __syncthreads();
    // sub-tile 0: k-cols [k0, k0+32)
    gld16(Ap + k0, asd);
    gld16(Ap + a64 + k0, asd + 2048);
    gld16(Bp + k0, bsd);
    gld16(Bp + b64 + k0, bsd + 2048);
    // sub-tile 1: k-cols [k0+32, k0+64)
    gld16(Ap + k0 + 32, asd + 4096);
    gld16(Ap + a64 + k0 + 32, asd + 6144);
    gld16(Bp + k0 + 32, bsd + 4096);
    gld16(Bp + b64 + k0 + 32, bsd + 6144);
    __syncthreads();
#pragma unroll
    for (int ks = 0; ks < 2; ++ks) {
      bf16x8 af[4], bfr[4];
#pragma unroll
      for (int i = 0; i < 4; ++i)
        af[i] = *(const bf16x8*)&As[ks * 4096 + (mo + i * 16 + fr) * 32 + fq];
#pragma unroll
      for (int i = 0; i < 4; ++i)
        bfr[i] = *(const bf16x8*)&Bs[ks * 4096 + (no + i * 16 + fr) * 32 + fq];
#pragma unroll
      for (int mi = 0; mi < 4; ++mi)
#pragma unroll
        for (int ni = 0; ni < 4; ++ni)
          acc[mi][ni] = __builtin_amdgcn_mfma_f32_16x16x32_bf16(af[mi], bfr[ni], acc[mi][ni], 0, 0, 0);
    }
  }

  // epilogue: C/D layout col=lane&15, row=(lane>>4)*4+reg (m89-verified)
  const long crow = bm + mo + ((lane >> 4) * 4);
  const long ccol = bn + no + (lane & 15);
#pragma unroll
  for (int mi = 0; mi < 4; ++mi) {
#pragma unroll
    for (int ni = 0; ni < 4; ++ni) {
      const long col = ccol + ni * 16;
      const float bv = HAS_BIAS ? bias[col] : 0.f;
#pragma unroll
      for (int r = 0; r < 4; ++r) {
        const long row = crow + mi * 16 + r;
        float v = acc[mi][ni][r] * scale + bv;
        if (HAS_RES) v += res[row * ldr + col];
        if (RELU) v = fmaxf(v, 0.f);
        const long idx = (long)z * sC + row * ldc + col;
        if (OUT_MODE == 0 || OUT_MODE == 2) ((float*)Cm)[idx] = v;
        if (OUT_MODE == 1) ((unsigned short*)Cm)[idx] = f2b(v);
        if (OUT_MODE == 2) C2[idx] = f2b(v);
      }
    }
  }
}

// ---------- row softmax over S with mask add, fp32 in -> bf16 out ----------
__global__ __launch_bounds__(256) void softmax_kernel(
    const float* __restrict__ Sf, const float* __restrict__ mask,
    unsigned short* __restrict__ Ab) {
  const long row = blockIdx.x;          // 0..MM-1 (b*SS+q)
  const int q = (int)(row & (SS - 1));
  const float* sr = Sf + row * SS;
  const float* mr = mask + (long)q * SS;
  const int tid = threadIdx.x;
  float v[8];
  float mx = -1e30f;
#pragma unroll
  for (int i = 0; i < 8; ++i) {
    int c = tid + i * 256;
    v[i] = sr[c] + mr[c];
    mx = fmaxf(mx, v[i]);
  }
#pragma unroll
  for (int off = 32; off > 0; off >>= 1) mx = fmaxf(mx, __shfl_xor(mx, off, 64));
  __shared__ float rm[4], rs[4];
  if ((tid & 63) == 0) rm[tid >> 6] = mx;
  __syncthreads();
  mx = fmaxf(fmaxf(rm[0], rm[1]), fmaxf(rm[2], rm[3]));
  float sum = 0.f;
#pragma unroll
  for (int i = 0; i < 8; ++i) { v[i] = __expf(v[i] - mx); sum += v[i]; }
#pragma unroll
  for (int off = 32; off > 0; off >>= 1) sum += __shfl_xor(sum, off, 64);
  if ((tid & 63) == 0) rs[tid >> 6] = sum;
  __syncthreads();
  sum = rs[0] + rs[1] + rs[2] + rs[3];
  const float inv = 1.f / sum;
  unsigned short* ar = Ab + row * SS;
#pragma unroll
  for (int i = 0; i < 8; ++i) ar[tid + i * 256] = f2b(v[i] * inv);
}

// ---------- in-place LayerNorm over H=1024 ----------
__global__ __launch_bounds__(256) void layernorm_kernel(
    float* __restrict__ Y, const float* __restrict__ g, const float* __restrict__ b) {
  const long row = blockIdx.x;
  float* y = Y + row * HH;
  const int tid = threadIdx.x;
  float v[4];
  float s = 0.f, ss = 0.f;
#pragma unroll
  for (int i = 0; i < 4; ++i) {
    v[i] = y[tid + i * 256];
    s += v[i]; ss += v[i] * v[i];
  }
#pragma unroll
  for (int off = 32; off > 0; off >>= 1) {
    s += __shfl_xor(s, off, 64);
    ss += __shfl_xor(ss, off, 64);
  }
  __shared__ float r1[4], r2[4];
  if ((tid & 63) == 0) { r1[tid >> 6] = s; r2[tid >> 6] = ss; }
  __syncthreads();
  s = r1[0] + r1[1] + r1[2] + r1[3];
  ss = r2[0] + r2[1] + r2[2] + r2[3];
  const float mu = s * (1.f / HH);
  const float var = ss * (1.f / HH) - mu * mu;
  const float rinv = rsqrtf(var + 1e-5f);
#pragma unroll
  for (int i = 0; i < 4; ++i) {
    int c = tid + i * 256;
    y[c] = (v[i] - mu) * rinv * g[c] + b[c];
  }
}

extern "C" void kernel_launch(void* const* d_in, const int* in_sizes, int n_in,
                              void* d_out, int out_size, void* d_ws, size_t ws_size,
                              hipStream_t stream) {
  (void)in_sizes; (void)n_in; (void)out_size; (void)ws_size;
  const float* x     = (const float*)d_in[0];
  const float* mask  = (const float*)d_in[1];
  const float* qW    = (const float*)d_in[2];
  const float* qb    = (const float*)d_in[3];
  const float* kW    = (const float*)d_in[4];
  const float* kb    = (const float*)d_in[5];
  const float* vW    = (const float*)d_in[6];
  const float* vb    = (const float*)d_in[7];
  const float* w1    = (const float*)d_in[8];
  const float* b1    = (const float*)d_in[9];
  const float* w2    = (const float*)d_in[10];
  const float* b2    = (const float*)d_in[11];
  const float* gamma = (const float*)d_in[12];
  const float* beta  = (const float*)d_in[13];
  float* out = (float*)d_out;

  char* ws = (char*)d_ws;
  size_t o = 0;
  auto alloc = [&](size_t bytes) { void* p = ws + o; o += (bytes + 255) & ~(size_t)255; return p; };
  unsigned short* Wqkv = (unsigned short*)alloc((size_t)3 * HH * HH * 2); // [3072][1024] (N,K) bf16
  unsigned short* w1t  = (unsigned short*)alloc((size_t)FF * HH * 2);     // [F][H]
  unsigned short* w2t  = (unsigned short*)alloc((size_t)HH * FF * 2);     // [H][F]
  float*          qkvb = (float*)alloc((size_t)3 * HH * 4);               // concat bias
  unsigned short* xb   = (unsigned short*)alloc((size_t)MM * HH * 2);     // x bf16
  unsigned short* QKVb = (unsigned short*)alloc((size_t)MM * 3 * HH * 2); // [M,3072] bf16
  unsigned short* Vt   = (unsigned short*)alloc((size_t)HH * MM * 2);     // [H][M] V^T bf16
  float*          attnf= (float*)alloc((size_t)MM * HH * 4);              // attn fp32 (residual)
  unsigned short* attnb= (unsigned short*)alloc((size_t)MM * HH * 2);     // attn bf16
  float*          Sf   = (float*)alloc((size_t)BB * SS * SS * 4);         // scores fp32; reused as h bf16
  unsigned short* Ab   = (unsigned short*)alloc((size_t)BB * SS * SS * 2);
  unsigned short* hb   = (unsigned short*)Sf;   // [M,F] bf16 (64MB, reuse Sf)

  const dim3 tb(32, 8);

  // 1. x -> bf16
  conv_f2b_kernel<<<MM * HH / 1024, 256, 0, stream>>>(x, xb, (long)MM * HH / 4);
  // 2. weight transposes (fp32 [K,N] -> bf16 [N,K]); QKV concatenated along N
  transpose_f2b_kernel<<<dim3(HH / 32, HH / 32), tb, 0, stream>>>(qW, Wqkv, HH, HH);
  transpose_f2b_kernel<<<dim3(HH / 32, HH / 32), tb, 0, stream>>>(kW, Wqkv + (size_t)HH * HH, HH, HH);
  transpose_f2b_kernel<<<dim3(HH / 32, HH / 32), tb, 0, stream>>>(vW, Wqkv + (size_t)2 * HH * HH, HH, HH);
  transpose_f2b_kernel<<<dim3(FF / 32, HH / 32), tb, 0, stream>>>(w1, w1t, HH, FF);
  transpose_f2b_kernel<<<dim3(HH / 32, FF / 32), tb, 0, stream>>>(w2, w2t, FF, HH);
  concat3_kernel<<<12, 256, 0, stream>>>(qb, kb, vb, qkvb);
  // 3. QKV = x * Wqkv^T + b, single GEMM, bf16 out [M,3072]
  gemm_bt_kernel<1, 0, 1, 0><<<dim3(3 * HH / 128, MM / 128, 1), 256, 0, stream>>>(
      xb, HH, 0, Wqkv, HH, 0, QKVb, 3 * HH, 0, nullptr, qkvb, nullptr, 0, 1.f, HH);
  // 4. V^T (bf16 [M,1024] slice of QKVb -> bf16 [1024,M])
  transpose_b2b_kernel<<<dim3(HH / 32, MM / 32), tb, 0, stream>>>(
      QKVb + 2 * HH, 3 * HH, Vt, MM, HH);
  // 5. S = Q K^T / sqrt(H), batched over BB
  gemm_bt_kernel<0, 0, 0, 0><<<dim3(SS / 128, SS / 128, BB), 256, 0, stream>>>(
      QKVb, 3 * HH, (long)SS * 3 * HH, QKVb + HH, 3 * HH, (long)SS * 3 * HH,
      Sf, SS, (long)SS * SS, nullptr, nullptr, nullptr, 0, 0.03125f, HH);
  // 6. A = softmax(S + mask) -> bf16
  softmax_kernel<<<MM, 256, 0, stream>>>(Sf, mask, Ab);
  // 7. attn = A V, batched; fp32 + bf16 dual output
  gemm_bt_kernel<2, 0, 0, 0><<<dim3(HH / 128, SS / 128, BB), 256, 0, stream>>>(
      Ab, SS, (long)SS * SS, Vt, MM, SS, attnf, HH, (long)SS * HH,
      attnb, nullptr, nullptr, 0, 1.f, SS);
  // 8. h = relu(attn w1 + b1) -> bf16
  gemm_bt_kernel<1, 1, 1, 0><<<dim3(FF / 128, MM / 128, 1), 256, 0, stream>>>(
      attnb, HH, 0, w1t, HH, 0, hb, FF, 0, nullptr, b1, nullptr, 0, 1.f, HH);
  // 9. y = attn + h w2 + b2 -> fp32 out
  gemm_bt_kernel<0, 0, 1, 1><<<dim3(HH / 128, MM / 128, 1), 256, 0, stream>>>(
      hb, FF, 0, w2t, FF, 0, out, HH, 0, nullptr, b2, attnf, HH, 1.f, FF);
  // 10. LayerNorm in place
  layernorm_kernel<<<MM, 256, 0, stream>>>(out, gamma, beta);
}